// Round 3
// baseline (296.554 us; speedup 1.0000x reference)
//
#include <hip/hip_runtime.h>
#include <math.h>
#include <cstddef>

#define HDIM 64
#define WDIM 2048
#define HW   (HDIM*WDIM)      // 131072
#define BATCH 2
#define CIN  64
#define COUT 64
#define XC   (3+CIN)          // 67
#define NPIX (BATCH*HW)       // 262144
#define NBLK (NPIX/64)        // 4096 blocks, 64 pixels each
#define NB2  (NBLK*2)         // 2 partial slots per block (px halves)
#define EPS  1e-5f

typedef short  short8  __attribute__((ext_vector_type(8)));
typedef float  f32x16  __attribute__((ext_vector_type(16)));

__device__ __forceinline__ unsigned short f2bf(float f) {
    unsigned int u = __float_as_uint(f);
    u += 0x7fff + ((u >> 16) & 1);        // round-to-nearest-even
    return (unsigned short)(u >> 16);
}

// LDS: phase-1 attention state + phase-2 V operand tile (A now global bf16).
// V rows padded 64->72 ushorts: b128 frag reads start at bank 4*mrow%32 ->
// 8 start groups, min 8 bank-cycles per wave access (conflict-free).
struct __align__(16) SmemA {
    float wsm[9][64];     // softmax(ws)[k] * mask[k], [k][px]
    float mk[9][64];      // mask[k], [k][px]
    float winv[64];       // 1/sum(exp(wc)) per px
    float wc[64][64];     // exp(wc_c - max) unnormalized, [c][px]
    union {
        unsigned short V[64][72];   // weighted feat [px][k] bf16
        float wspart[9][4][64];     // phase-1 partial max
    } u;
};

// one-time per launch: w_agg fp32 -> bf16 [64][576]
__global__ __launch_bounds__(256)
void kernelW(const float* __restrict__ w_agg, unsigned short* __restrict__ wbf)
{
    int i = blockIdx.x*256 + threadIdx.x;    // 9216 float4s
    float4 t = ((const float4*)w_agg)[i];
    unsigned long long pk =  (unsigned long long)f2bf(t.x)
                          | ((unsigned long long)f2bf(t.y)<<16)
                          | ((unsigned long long)f2bf(t.z)<<32)
                          | ((unsigned long long)f2bf(t.w)<<48);
    *(unsigned long long*)(wbf + (size_t)i*4) = pk;
}

__global__ __launch_bounds__(256, 4)
void kernelA(const float* __restrict__ x, const int* __restrict__ mask,
             const float* __restrict__ w_sp, const float* __restrict__ b_sp,
             const float* __restrict__ w_ch, const float* __restrict__ b_ch,
             const unsigned short* __restrict__ wbf,
             float* __restrict__ out, float* __restrict__ psum, float* __restrict__ psq)
{
    __shared__ SmemA s;
    const int tid = threadIdx.x;
    const int bid = blockIdx.x;
    const int b  = bid >> 11;
    const int r  = bid & 2047;
    const int h  = r >> 5;
    const int w0 = (r & 31) << 6;

    const int px = tid & 63;
    const int q  = tid >> 6;

    // ---------------- phase 1: per-pixel attention weights ----------------
    float p[9][4];
    float mkr[9];
    {
        const int wpix = w0 + px;
        #pragma unroll
        for (int k = 0; k < 9; ++k) {
            int hh = h + k/3 - 1;
            int ww = wpix + k%3 - 1;
            bool in = (hh >= 0) && (hh < HDIM) && (ww >= 0) && (ww < WDIM);
            float p0=0.f, p1=0.f, p2=0.f, mv=0.f;
            if (in) {
                size_t base = ((size_t)(b*XC)*HDIM + hh)*(size_t)WDIM + ww;
                p0 = x[base];
                p1 = x[base + (size_t)HW];
                p2 = x[base + 2*(size_t)HW];
                mv = (float)mask[((size_t)b*HDIM + hh)*(size_t)WDIM + ww];
            }
            p[k][0]=p0; p[k][1]=p1; p[k][2]=p2;
            p[k][3]=sqrtf(p0*p0 + p1*p1 + p2*p2);
            mkr[k]=mv;
        }
        float c0=p[4][0], c1=p[4][1], c2=p[4][2], c3=p[4][3];
        #pragma unroll
        for (int k = 0; k < 9; ++k) {
            p[k][0]-=c0; p[k][1]-=c1; p[k][2]-=c2; p[k][3]-=c3;
        }
    }

    float wsp[9];
    #pragma unroll
    for (int k=0;k<9;++k) wsp[k] = -1e30f;
    for (int cc = 0; cc < 16; ++cc) {
        int c = q*16 + cc;                       // wave-uniform -> scalar loads
        float a0=w_sp[c*4+0], a1=w_sp[c*4+1], a2=w_sp[c*4+2], a3=w_sp[c*4+3], bs=b_sp[c];
        float d0=w_ch[c*4+0], d1=w_ch[c*4+1], d2=w_ch[c*4+2], d3=w_ch[c*4+3], bc=b_ch[c];
        // tap 4: p[4] is exactly 0 after centering -> sv=bs, tv=bc
        float tmax = bc;
        wsp[4] = fmaxf(wsp[4], bs);
        #pragma unroll
        for (int k=0;k<9;++k) {
            if (k == 4) continue;
            float sv = fmaf(p[k][0],a0, fmaf(p[k][1],a1, fmaf(p[k][2],a2, fmaf(p[k][3],a3, bs))));
            wsp[k] = fmaxf(wsp[k], sv);
            float tv = fmaf(p[k][0],d0, fmaf(p[k][1],d1, fmaf(p[k][2],d2, fmaf(p[k][3],d3, bc))));
            tmax = fmaxf(tmax, tv);
        }
        s.wc[c][px] = tmax;
    }
    #pragma unroll
    for (int k=0;k<9;++k) s.u.wspart[k][q][px] = wsp[k];
    __syncthreads();

    if (q == 0) {
        float v[9]; float mx = -1e30f;
        #pragma unroll
        for (int k=0;k<9;++k) {
            float a = s.u.wspart[k][0][px];
            a = fmaxf(a, s.u.wspart[k][1][px]);
            a = fmaxf(a, s.u.wspart[k][2][px]);
            a = fmaxf(a, s.u.wspart[k][3][px]);
            v[k]=a; mx=fmaxf(mx,a);
        }
        float sum=0.f;
        #pragma unroll
        for (int k=0;k<9;++k) { v[k]=__expf(v[k]-mx); sum+=v[k]; }
        float inv = 1.0f/sum;
        #pragma unroll
        for (int k=0;k<9;++k) {
            s.wsm[k][px] = v[k]*inv*mkr[k];
            s.mk[k][px]  = mkr[k];
        }
    } else if (q == 1) {
        float mx=-1e30f;
        for (int c=0;c<64;++c) mx = fmaxf(mx, s.wc[c][px]);
        float sum=0.f;
        for (int c=0;c<64;++c) {
            float e = __expf(s.wc[c][px]-mx);
            s.wc[c][px] = e;
            sum += e;
        }
        s.winv[px] = 1.0f/sum;
    }
    __syncthreads();

    // ---------------- phase 2: bf16 MFMA GEMM out[co][px] = sum_f A*V -------
    const int lane = tid & 63;
    const int wv   = tid >> 6;
    const int mrow = lane & 31;
    const int half = lane >> 5;
    const int co0  = (wv & 1) * 32;
    const int px0  = (wv >> 1) * 32;

    // per-lane A base: all 36 K-step fragments are imm offsets off this
    const unsigned short* abase = wbf + (size_t)(co0+mrow)*576 + half*8;

    f32x16 acc;
    #pragma unroll
    for (int i=0;i<16;++i) acc[i]=0.f;

    for (int kk = 0; kk < 9; ++kk) {
        // issue A-frag global loads early (L2-hot, overlap with V staging)
        short8 af[4];
        #pragma unroll
        for (int ks=0; ks<4; ++ks)
            af[ks] = *(const short8*)(abase + kk*64 + ks*16);

        // stage V chunk: V[px][c] = bf16((a_k + m_k*inv*e_c) * feat)
        {
            int di = kk/3 - 1, dj = (kk%3) - 1;
            int hh = h + di;
            int ww = w0 + px + dj;
            bool inb = (hh>=0) && (hh<HDIM) && (ww>=0) && (ww<WDIM);
            int hhc = hh<0?0:(hh>HDIM-1?HDIM-1:hh);
            int wwc = ww<0?0:(ww>WDIM-1?WDIM-1:ww);
            const float* xb = x + ((size_t)(b*XC + 3)*HDIM + hhc)*(size_t)WDIM + wwc;
            float a_k = s.wsm[kk][px];
            float m2  = s.mk[kk][px] * s.winv[px];
            unsigned short vv[16];
            #pragma unroll
            for (int j=0;j<16;++j) {
                unsigned c = 16u*q + j;
                float f = inb ? xb[(size_t)c*HW] : 0.f;
                vv[j] = f2bf(fmaf(m2, s.wc[c][px], a_k) * f);
            }
            unsigned short* vp = &s.u.V[px][16*q];
            short8 lo, hi;
            #pragma unroll
            for (int j=0;j<8;++j) { lo[j]=(short)vv[j]; hi[j]=(short)vv[8+j]; }
            *(short8*)vp       = lo;
            *(short8*)(vp + 8) = hi;
        }
        __syncthreads();
        #pragma unroll
        for (int ks=0; ks<4; ++ks) {
            short8 bf = *(const short8*)&s.u.V[px0+mrow][ks*16 + half*8];
            acc = __builtin_amdgcn_mfma_f32_32x32x16_bf16(af[ks], bf, acc, 0, 0, 0);
        }
        __syncthreads();
    }

    // ---------------- epilogue: out (pre-BN) + per-channel partials ----------
    const int pxg = w0 + px0 + mrow;
    #pragma unroll
    for (int reg=0; reg<16; ++reg) {
        int row = (reg&3) + 8*(reg>>2) + 4*half;   // C/D layout, 32x32x16
        int co  = co0 + row;
        float v = acc[reg];
        out[((size_t)(b*COUT+co))*HW + (size_t)h*WDIM + pxg] = v;
        float s1 = v, s2 = v*v;
        #pragma unroll
        for (int m=1; m<32; m<<=1) {
            s1 += __shfl_xor(s1, m, 64);
            s2 += __shfl_xor(s2, m, 64);
        }
        if (mrow == 0) {
            psum[(size_t)co*NB2 + bid*2 + (wv>>1)] = s1;
            psq [(size_t)co*NB2 + bid*2 + (wv>>1)] = s2;
        }
    }
}

__global__ __launch_bounds__(256)
void kernelB(const float* __restrict__ psum, const float* __restrict__ psq,
             float* __restrict__ stats)
{
    int co = blockIdx.x;
    int tid = threadIdx.x;
    float s=0.f, sq=0.f;
    for (int j = tid; j < NB2; j += 256) {
        s  += psum[(size_t)co*NB2 + j];
        sq += psq [(size_t)co*NB2 + j];
    }
    #pragma unroll
    for (int m=1; m<64; m<<=1) { s += __shfl_xor(s,m,64); sq += __shfl_xor(sq,m,64); }
    __shared__ float rs[4], rq[4];
    int wv = tid>>6;
    if ((tid&63)==0){ rs[wv]=s; rq[wv]=sq; }
    __syncthreads();
    if (tid==0) {
        float S = rs[0]+rs[1]+rs[2]+rs[3];
        float Q = rq[0]+rq[1]+rq[2]+rq[3];
        float mu = S / (float)NPIX;
        float var = Q/(float)NPIX - mu*mu;
        stats[co]      = mu;
        stats[64+co]   = rsqrtf(var + EPS);
    }
}

__global__ __launch_bounds__(256)
void kernelC(float* __restrict__ out, const float* __restrict__ stats,
             const float* __restrict__ gamma, const float* __restrict__ beta)
{
    size_t idx8 = (size_t)blockIdx.x*256 + threadIdx.x;
    size_t flat = idx8*8;
    int co = (int)((flat >> 17) & 63);          // 8 | 131072 -> same co for both
    float mu = stats[co], rstd = stats[64+co];
    float g  = gamma[co]*rstd;
    float bb = fmaf(-mu, g, beta[co]);
    #pragma unroll
    for (int t=0;t<2;++t) {
        float4 v = *(float4*)(out + flat + t*4);
        v.x = fmaxf(fmaf(v.x, g, bb), 0.f);
        v.y = fmaxf(fmaf(v.y, g, bb), 0.f);
        v.z = fmaxf(fmaf(v.z, g, bb), 0.f);
        v.w = fmaxf(fmaf(v.w, g, bb), 0.f);
        *(float4*)(out + flat + t*4) = v;
    }
}

extern "C" void kernel_launch(void* const* d_in, const int* in_sizes, int n_in,
                              void* d_out, int out_size, void* d_ws, size_t ws_size,
                              hipStream_t stream)
{
    const float* x     = (const float*)d_in[0];
    const int*   mask  = (const int*)  d_in[1];
    const float* w_sp  = (const float*)d_in[2];
    const float* b_sp  = (const float*)d_in[3];
    const float* w_ch  = (const float*)d_in[4];
    const float* b_ch  = (const float*)d_in[5];
    const float* w_agg = (const float*)d_in[6];
    const float* gamma = (const float*)d_in[7];
    const float* beta  = (const float*)d_in[8];
    float* out  = (float*)d_out;
    float* psum = (float*)d_ws;
    float* psq  = psum + (size_t)COUT*NB2;
    float* stats= psq  + (size_t)COUT*NB2;
    unsigned short* wbf = (unsigned short*)(stats + 128);   // 16B-aligned

    kernelW<<<36, 256, 0, stream>>>(w_agg, wbf);
    kernelA<<<NBLK, 256, 0, stream>>>(x, mask, w_sp, b_sp, w_ch, b_ch, wbf, out, psum, psq);
    kernelB<<<COUT, 256, 0, stream>>>(psum, psq, stats);
    int grid_c = (NPIX*COUT/8)/256;   // 8192
    kernelC<<<grid_c, 256, 0, stream>>>(out, stats, gamma, beta);
}

// Round 4
// 261.783 us; speedup vs baseline: 1.1328x; 1.1328x over previous
//
#include <hip/hip_runtime.h>
#include <hip/hip_bf16.h>
#include <math.h>
#include <cstddef>

#define HDIM 64
#define WDIM 2048
#define HW   (HDIM*WDIM)      // 131072
#define BATCH 2
#define CIN  64
#define COUT 64
#define XC   (3+CIN)          // 67
#define NPIX (BATCH*HW)       // 262144
#define NBLK (NPIX/64)        // 4096 blocks, 64 pixels each
#define NB2  (NBLK*2)         // 2 partial slots per block (px halves)
#define EPS  1e-5f

typedef short  short8  __attribute__((ext_vector_type(8)));
typedef float  f32x16  __attribute__((ext_vector_type(16)));

__device__ __forceinline__ unsigned short f2bf(float f) {
    unsigned int u = __float_as_uint(f);
    u += 0x7fff + ((u >> 16) & 1);        // round-to-nearest-even
    return (unsigned short)(u >> 16);
}

// LDS: phase-1 attention state + phase-2 V operand tile.
// V rows padded 64->72 ushorts: b128 frag reads start bank 4*mrow%32 ->
// 8 start groups = conflict-free (measured 0 conflicts rounds 2-3).
struct __align__(16) SmemA {
    float wsm[9][64];     // softmax(ws)[k] * mask[k], [k][px]
    float mk[9][64];      // mask[k], [k][px]
    float winv[64];       // 1/sum(exp(wc)) per px
    float wc[64][64];     // exp(wc_c - max) unnormalized, [c][px]
    union {
        unsigned short V[64][72];   // weighted feat [px][k] bf16
        float wspart[9][4][64];     // phase-1 partial max
    } u;
};

// one-time: w_agg fp32 -> bf16, PRE-SWIZZLED into MFMA fragment order:
// wbf[((kk*4+ks)*2+half)*64 + co][8] = w_agg[co][kk*64+ks*16+half*8 .. +8]
// so a wave's A-frag load (lane = (mrow,half), row co0+mrow) is 32x16B
// contiguous per half -> fully coalesced, L2-resident (74 KB).
__global__ __launch_bounds__(256)
void kernelW(const float* __restrict__ w_agg, unsigned short* __restrict__ wbf)
{
    int t = blockIdx.x*256 + threadIdx.x;    // 4608 threads total
    int co  = t / 72;
    int rem = t % 72;
    int kk  = rem >> 3;
    int ks  = (rem >> 1) & 3;
    int half= rem & 1;
    const float* src = w_agg + (size_t)co*576 + kk*64 + ks*16 + half*8;
    unsigned long long pk0 = 0, pk1 = 0;
    #pragma unroll
    for (int j=0;j<4;++j) pk0 |= (unsigned long long)f2bf(src[j])   << (16*j);
    #pragma unroll
    for (int j=0;j<4;++j) pk1 |= (unsigned long long)f2bf(src[4+j]) << (16*j);
    unsigned long long* dst =
        (unsigned long long*)(wbf + ((size_t)(((kk*4+ks)*2+half)*64 + co))*8);
    dst[0] = pk0; dst[1] = pk1;
}

__global__ __launch_bounds__(256, 4)
void kernelA(const float* __restrict__ x, const int* __restrict__ mask,
             const float* __restrict__ w_sp, const float* __restrict__ b_sp,
             const float* __restrict__ w_ch, const float* __restrict__ b_ch,
             const unsigned short* __restrict__ wbf,
             float* __restrict__ out, float* __restrict__ psum, float* __restrict__ psq)
{
    __shared__ SmemA s;
    const int tid = threadIdx.x;
    const int bid = blockIdx.x;
    const int b  = bid >> 11;
    const int r  = bid & 2047;
    const int h  = r >> 5;
    const int w0 = (r & 31) << 6;

    const int px = tid & 63;
    const int q  = tid >> 6;

    // ---------------- phase 1: per-pixel attention weights ----------------
    float p[9][4];
    float mkr[9];
    {
        const int wpix = w0 + px;
        #pragma unroll
        for (int k = 0; k < 9; ++k) {
            int hh = h + k/3 - 1;
            int ww = wpix + k%3 - 1;
            bool in = (hh >= 0) && (hh < HDIM) && (ww >= 0) && (ww < WDIM);
            float p0=0.f, p1=0.f, p2=0.f, mv=0.f;
            if (in) {
                size_t base = ((size_t)(b*XC)*HDIM + hh)*(size_t)WDIM + ww;
                p0 = x[base];
                p1 = x[base + (size_t)HW];
                p2 = x[base + 2*(size_t)HW];
                mv = (float)mask[((size_t)b*HDIM + hh)*(size_t)WDIM + ww];
            }
            p[k][0]=p0; p[k][1]=p1; p[k][2]=p2;
            p[k][3]=sqrtf(p0*p0 + p1*p1 + p2*p2);
            mkr[k]=mv;
        }
        float c0=p[4][0], c1=p[4][1], c2=p[4][2], c3=p[4][3];
        #pragma unroll
        for (int k = 0; k < 9; ++k) {
            p[k][0]-=c0; p[k][1]-=c1; p[k][2]-=c2; p[k][3]-=c3;
        }
    }

    float wsp[9];
    #pragma unroll
    for (int k=0;k<9;++k) wsp[k] = -1e30f;
    for (int cc = 0; cc < 16; ++cc) {
        int c = q*16 + cc;                       // wave-uniform -> scalar loads
        float a0=w_sp[c*4+0], a1=w_sp[c*4+1], a2=w_sp[c*4+2], a3=w_sp[c*4+3], bs=b_sp[c];
        float d0=w_ch[c*4+0], d1=w_ch[c*4+1], d2=w_ch[c*4+2], d3=w_ch[c*4+3], bc=b_ch[c];
        // tap 4: p[4] == 0 after centering -> sv=bs, tv=bc
        float tmax = bc;
        wsp[4] = fmaxf(wsp[4], bs);
        #pragma unroll
        for (int k=0;k<9;++k) {
            if (k == 4) continue;
            float sv = fmaf(p[k][0],a0, fmaf(p[k][1],a1, fmaf(p[k][2],a2, fmaf(p[k][3],a3, bs))));
            wsp[k] = fmaxf(wsp[k], sv);
            float tv = fmaf(p[k][0],d0, fmaf(p[k][1],d1, fmaf(p[k][2],d2, fmaf(p[k][3],d3, bc))));
            tmax = fmaxf(tmax, tv);
        }
        s.wc[c][px] = tmax;
    }
    #pragma unroll
    for (int k=0;k<9;++k) s.u.wspart[k][q][px] = wsp[k];
    __syncthreads();

    if (q == 0) {
        float v[9]; float mx = -1e30f;
        #pragma unroll
        for (int k=0;k<9;++k) {
            float a = s.u.wspart[k][0][px];
            a = fmaxf(a, s.u.wspart[k][1][px]);
            a = fmaxf(a, s.u.wspart[k][2][px]);
            a = fmaxf(a, s.u.wspart[k][3][px]);
            v[k]=a; mx=fmaxf(mx,a);
        }
        float sum=0.f;
        #pragma unroll
        for (int k=0;k<9;++k) { v[k]=__expf(v[k]-mx); sum+=v[k]; }
        float inv = 1.0f/sum;
        #pragma unroll
        for (int k=0;k<9;++k) {
            s.wsm[k][px] = v[k]*inv*mkr[k];
            s.mk[k][px]  = mkr[k];
        }
    } else if (q == 1) {
        float mx=-1e30f;
        for (int c=0;c<64;++c) mx = fmaxf(mx, s.wc[c][px]);
        float sum=0.f;
        for (int c=0;c<64;++c) {
            float e = __expf(s.wc[c][px]-mx);
            s.wc[c][px] = e;
            sum += e;
        }
        s.winv[px] = 1.0f/sum;
    }
    __syncthreads();

    // ---------------- phase 2: bf16 MFMA GEMM out[co][px] = sum_f A*V -------
    const int lane = tid & 63;
    const int wv   = tid >> 6;
    const int mrow = lane & 31;
    const int half = lane >> 5;
    const int co0  = (wv & 1) * 32;
    const int px0  = (wv >> 1) * 32;

    const short8* aswz = (const short8*)wbf;   // [((kk*4+ks)*2+half)*64 + co]

    f32x16 acc;
    #pragma unroll
    for (int i=0;i<16;++i) acc[i]=0.f;

    for (int kk = 0; kk < 9; ++kk) {
        // A-frag loads: coalesced (32 lanes x 16B contiguous per half), L2-hot;
        // issued before V staging so vmcnt overlaps the LDS work.
        short8 af[4];
        #pragma unroll
        for (int ks=0; ks<4; ++ks)
            af[ks] = aswz[(size_t)(((kk*4+ks)*2+half)*64) + co0 + mrow];

        // stage V chunk: V[px][c] = bf16((a_k + m_k*inv*e_c) * feat), pair-cvt
        {
            int di = kk/3 - 1, dj = (kk%3) - 1;
            int hh = h + di;
            int ww = w0 + px + dj;
            bool inb = (hh>=0) && (hh<HDIM) && (ww>=0) && (ww<WDIM);
            int hhc = hh<0?0:(hh>HDIM-1?HDIM-1:hh);
            int wwc = ww<0?0:(ww>WDIM-1?WDIM-1:ww);
            const float* xb = x + ((size_t)(b*XC + 3)*HDIM + hhc)*(size_t)WDIM + wwc;
            float a_k = s.wsm[kk][px];
            float m2  = s.mk[kk][px] * s.winv[px];
            unsigned int packed[8];
            #pragma unroll
            for (int j=0;j<8;++j) {
                unsigned c0 = 16u*q + 2u*j;
                float f0 = inb ? xb[(size_t)c0*HW]       : 0.f;
                float f1 = inb ? xb[(size_t)(c0+1)*HW]   : 0.f;
                float w0f = fmaf(m2, s.wc[c0][px],   a_k) * f0;
                float w1f = fmaf(m2, s.wc[c0+1][px], a_k) * f1;
                __hip_bfloat162 h2 = __float22bfloat162_rn(float2{w0f, w1f});
                unsigned int u; __builtin_memcpy(&u, &h2, 4);
                packed[j] = u;
            }
            uint4* vp = (uint4*)&s.u.V[px][16*q];
            vp[0] = uint4{packed[0],packed[1],packed[2],packed[3]};
            vp[1] = uint4{packed[4],packed[5],packed[6],packed[7]};
        }
        __syncthreads();
        #pragma unroll
        for (int ks=0; ks<4; ++ks) {
            short8 bf = *(const short8*)&s.u.V[px0+mrow][ks*16 + half*8];
            acc = __builtin_amdgcn_mfma_f32_32x32x16_bf16(af[ks], bf, acc, 0, 0, 0);
        }
        __syncthreads();
    }

    // ---------------- epilogue: out (pre-BN) + per-channel partials ----------
    const int pxg = w0 + px0 + mrow;
    #pragma unroll
    for (int reg=0; reg<16; ++reg) {
        int row = (reg&3) + 8*(reg>>2) + 4*half;   // C/D layout, 32x32x16
        int co  = co0 + row;
        float v = acc[reg];
        out[((size_t)(b*COUT+co))*HW + (size_t)h*WDIM + pxg] = v;
        float s1 = v, s2 = v*v;
        #pragma unroll
        for (int m=1; m<32; m<<=1) {
            s1 += __shfl_xor(s1, m, 64);
            s2 += __shfl_xor(s2, m, 64);
        }
        if (mrow == 0) {
            psum[(size_t)co*NB2 + bid*2 + (wv>>1)] = s1;
            psq [(size_t)co*NB2 + bid*2 + (wv>>1)] = s2;
        }
    }
}

__global__ __launch_bounds__(256)
void kernelB(const float* __restrict__ psum, const float* __restrict__ psq,
             float* __restrict__ stats)
{
    int co = blockIdx.x;
    int tid = threadIdx.x;
    float s=0.f, sq=0.f;
    for (int j = tid; j < NB2; j += 256) {
        s  += psum[(size_t)co*NB2 + j];
        sq += psq [(size_t)co*NB2 + j];
    }
    #pragma unroll
    for (int m=1; m<64; m<<=1) { s += __shfl_xor(s,m,64); sq += __shfl_xor(sq,m,64); }
    __shared__ float rs[4], rq[4];
    int wv = tid>>6;
    if ((tid&63)==0){ rs[wv]=s; rq[wv]=sq; }
    __syncthreads();
    if (tid==0) {
        float S = rs[0]+rs[1]+rs[2]+rs[3];
        float Q = rq[0]+rq[1]+rq[2]+rq[3];
        float mu = S / (float)NPIX;
        float var = Q/(float)NPIX - mu*mu;
        stats[co]      = mu;
        stats[64+co]   = rsqrtf(var + EPS);
    }
}

__global__ __launch_bounds__(256)
void kernelC(float* __restrict__ out, const float* __restrict__ stats,
             const float* __restrict__ gamma, const float* __restrict__ beta)
{
    size_t idx8 = (size_t)blockIdx.x*256 + threadIdx.x;
    size_t flat = idx8*8;
    int co = (int)((flat >> 17) & 63);
    float mu = stats[co], rstd = stats[64+co];
    float g  = gamma[co]*rstd;
    float bb = fmaf(-mu, g, beta[co]);
    #pragma unroll
    for (int t=0;t<2;++t) {
        float4 v = *(float4*)(out + flat + t*4);
        v.x = fmaxf(fmaf(v.x, g, bb), 0.f);
        v.y = fmaxf(fmaf(v.y, g, bb), 0.f);
        v.z = fmaxf(fmaf(v.z, g, bb), 0.f);
        v.w = fmaxf(fmaf(v.w, g, bb), 0.f);
        *(float4*)(out + flat + t*4) = v;
    }
}

extern "C" void kernel_launch(void* const* d_in, const int* in_sizes, int n_in,
                              void* d_out, int out_size, void* d_ws, size_t ws_size,
                              hipStream_t stream)
{
    const float* x     = (const float*)d_in[0];
    const int*   mask  = (const int*)  d_in[1];
    const float* w_sp  = (const float*)d_in[2];
    const float* b_sp  = (const float*)d_in[3];
    const float* w_ch  = (const float*)d_in[4];
    const float* b_ch  = (const float*)d_in[5];
    const float* w_agg = (const float*)d_in[6];
    const float* gamma = (const float*)d_in[7];
    const float* beta  = (const float*)d_in[8];
    float* out  = (float*)d_out;
    float* psum = (float*)d_ws;
    float* psq  = psum + (size_t)COUT*NB2;
    float* stats= psq  + (size_t)COUT*NB2;
    unsigned short* wbf = (unsigned short*)(stats + 128);   // 16B-aligned

    kernelW<<<18, 256, 0, stream>>>(w_agg, wbf);
    kernelA<<<NBLK, 256, 0, stream>>>(x, mask, w_sp, b_sp, w_ch, b_ch, wbf, out, psum, psq);
    kernelB<<<COUT, 256, 0, stream>>>(psum, psq, stats);
    int grid_c = (NPIX*COUT/8)/256;   // 8192
    kernelC<<<grid_c, 256, 0, stream>>>(out, stats, gamma, beta);
}